// Round 26
// baseline (213.837 us; speedup 1.0000x reference)
//
#include <hip/hip_runtime.h>
#include <stdint.h>

#define Bn 2
#define Tn 2048
#define Cn 2048
#define NHEAD 32
#define NKVH 8
#define HDIM 64
#define Mn (Bn*Tn)        // 4096
#define NQKV 3072         // 2048 Q | 512 K | 512 V
#define KOFF 2048
#define VOFF 2560

typedef __attribute__((ext_vector_type(8))) short bf16x8;
typedef __attribute__((ext_vector_type(4))) float f32x4;

#define AS1 __attribute__((address_space(1)))
#define AS3 __attribute__((address_space(3)))
#define GLOAD_LDS16(g, l) __builtin_amdgcn_global_load_lds((const AS1 void*)(g), (AS3 void*)(l), 16, 0, 0)

#define SCL 0.18033688f  /* 0.125 * log2(e) — folded into Q during attn's in-register rope */

#define SYNC_FENCE() __builtin_amdgcn_sched_barrier(0)
#define WAIT_VM_N(N_) do { asm volatile("s_waitcnt vmcnt(" #N_ ")" ::: "memory"); SYNC_FENCE(); } while (0)
#define BARRIER_RAW() do { __builtin_amdgcn_s_barrier(); SYNC_FENCE(); } while (0)

__device__ __forceinline__ unsigned short f2bf(float f) {
    union { float f; unsigned u; } v; v.f = f;
    return (unsigned short)((v.u + 0x7fffu + ((v.u >> 16) & 1u)) >> 16);
}
__device__ __forceinline__ float bf2f(unsigned short b) {
    union { unsigned u; float f; } v; v.u = ((unsigned)b) << 16;
    return v.f;
}

// ---------------- elementwise fp32 -> bf16 (vectorized) ----------------
__global__ void convert_f32_bf16(const float* __restrict__ src,
                                 unsigned short* __restrict__ dst, int n4) {
    int i = blockIdx.x * blockDim.x + threadIdx.x;
    if (i >= n4) return;
    float4 f = ((const float4*)src)[i];
    ushort4 o;
    o.x = f2bf(f.x); o.y = f2bf(f.y); o.z = f2bf(f.z); o.w = f2bf(f.w);
    ((ushort4*)dst)[i] = o;
}

// ---------------- transpose + convert: src (K x N) fp32 -> dst (N x K) bf16 ----------------
__global__ void transpose_convert(const float* __restrict__ src,
                                  unsigned short* __restrict__ dst, int K, int N) {
    __shared__ float tile[32][33];
    int k0 = blockIdx.x * 32, n0 = blockIdx.y * 32;
    int tx = threadIdx.x, ty = threadIdx.y;  // 32 x 8
    #pragma unroll
    for (int yy = 0; yy < 32; yy += 8)
        tile[ty + yy][tx] = src[(size_t)(k0 + ty + yy) * N + n0 + tx];
    __syncthreads();
    #pragma unroll
    for (int yy = 0; yy < 32; yy += 8)
        dst[(size_t)(n0 + ty + yy) * K + k0 + tx] = f2bf(tile[tx][ty + yy]);
}

// ---------------- merged Wq|Wk|Wv transpose -> Wqkvt[3072][2048] ----------------
__global__ void transpose_wqkv(const float* __restrict__ Wq, const float* __restrict__ Wk,
                               const float* __restrict__ Wv, unsigned short* __restrict__ dst) {
    __shared__ float tile[32][33];
    int k0 = blockIdx.x * 32, n0 = blockIdx.y * 32;  // n0 in [0,3072)
    const float* src; int srcN, c0;
    if (n0 < 2048)      { src = Wq; srcN = 2048; c0 = n0; }
    else if (n0 < 2560) { src = Wk; srcN = 512;  c0 = n0 - 2048; }
    else                { src = Wv; srcN = 512;  c0 = n0 - 2560; }
    int tx = threadIdx.x, ty = threadIdx.y;  // 32 x 8
    #pragma unroll
    for (int yy = 0; yy < 32; yy += 8)
        tile[ty + yy][tx] = src[(size_t)(k0 + ty + yy) * srcN + c0 + tx];
    __syncthreads();
    #pragma unroll
    for (int yy = 0; yy < 32; yy += 8)
        dst[(size_t)(n0 + ty + yy) * Cn + k0 + tx] = f2bf(tile[tx][ty + yy]);
}

// ---------------- RoPE tables: ct/st [Tn][32] fp32 ----------------
__global__ void rope_tables(float* __restrict__ ct, float* __restrict__ st) {
    int i = blockIdx.x * blockDim.x + threadIdx.x;  // Tn*32
    int t = i >> 5, d = i & 31;
    float invf = powf(10000.0f, -(float)d / 32.0f);
    float f = (float)t * invf;
    ct[i] = cosf(f);
    st[i] = sinf(f);
}

// ---------------- RoPE in-place on K heads only (no scale) ----------------
__global__ void rope_k(unsigned short* __restrict__ qkv,
                       const float* __restrict__ ct, const float* __restrict__ st) {
    int i = blockIdx.x * blockDim.x + threadIdx.x;  // Mn * 8 * 32
    int p = i & 31;
    int kvh = (i >> 5) & 7;
    int bt = i >> 8;
    int t = bt & (Tn - 1);
    size_t base = (size_t)bt * NQKV + KOFF + kvh * 64;
    float v0 = bf2f(qkv[base + p]);
    float v1 = bf2f(qkv[base + p + 32]);
    float c = ct[t * 32 + p], s = st[t * 32 + p];
    qkv[base + p]      = f2bf(v0 * c - v1 * s);
    qkv[base + p + 32] = f2bf(v1 * c + v0 * s);
}

// ---------------- V transpose: QKV V-part -> Vt[b][kvh][d][t] (bf16) ----------------
__global__ void transpose_v(const unsigned short* __restrict__ qkv,
                            unsigned short* __restrict__ vt) {
    __shared__ unsigned short tile[32][33];
    int t0 = blockIdx.x * 32;
    int b = blockIdx.y >> 3, kvh = blockIdx.y & 7;
    int d0 = blockIdx.z * 32;
    int tx = threadIdx.x, ty = threadIdx.y;  // 32 x 8
    #pragma unroll
    for (int yy = 0; yy < 32; yy += 8)
        tile[ty + yy][tx] = qkv[(size_t)(b * Tn + t0 + ty + yy) * NQKV + VOFF + kvh * 64 + d0 + tx];
    __syncthreads();
    #pragma unroll
    for (int yy = 0; yy < 32; yy += 8)
        vt[(size_t)((b * 8 + kvh) * 64 + d0 + ty + yy) * Tn + t0 + tx] = tile[tx][ty + yy];
}

// ---------------- Pipelined GEMM template: C = A[M,K] @ Bt[N,K]^T ----------------
// BK=64, double-buffered LDS, counted-vmcnt schedule (loads never drained to 0
// in the main loop), raw barriers. BF16OUT selects output dtype.
template <int BM, int BN, int WMv, int WNv, bool BF16OUT, bool SWZ>
__global__ __launch_bounds__(WMv * WNv * 64, 2) void gemm_pipe(
    const unsigned short* __restrict__ A, const unsigned short* __restrict__ Bt,
    unsigned short* __restrict__ outb, float* __restrict__ outf, int N, int K) {
    constexpr int THREADS = WMv * WNv * 64;
    constexpr int MR = BM / WMv / 16;           // m-frags per wave
    constexpr int NR = BN / WNv / 16;           // n-frags per wave
    constexpr int LA = (BM * 64 * 2) / (THREADS * 16);  // A gload_lds per thread
    constexpr int LB = (BN * 64 * 2) / (THREADS * 16);  // B gload_lds per thread

    __shared__ unsigned short sA[2][BM * 64];
    __shared__ unsigned short sB[2][BN * 64];

    int tid = threadIdx.x;
    int wid = tid >> 6, lane = tid & 63;
    int wm = wid / WNv, wn = wid % WNv;
    int g = lane >> 4, r16 = lane & 15;

    int bx, by;
    if (SWZ) {
        int nwg = gridDim.x * gridDim.y;
        int lid = blockIdx.y * gridDim.x + blockIdx.x;
        int swz = (lid & 7) * (nwg >> 3) + (lid >> 3);
        bx = swz % gridDim.x; by = swz / gridDim.x;
    } else {
        bx = blockIdx.x; by = blockIdx.y;
    }
    int brow = by * BM, bcol = bx * BN;

    int NT = K / 64;

    auto stage = [&](int kt, int b) {
        #pragma unroll
        for (int li = 0; li < LA; li++) {
            int cb = li * (THREADS * 16) + wid * 1024;
            int bo = cb + lane * 16;
            int row = bo >> 7;
            int coff = (bo & 127) ^ ((row & 7) << 4);
            GLOAD_LDS16(A + (size_t)(brow + row) * K + kt * 64 + (coff >> 1),
                        (char*)&sA[b][0] + cb);
        }
        #pragma unroll
        for (int li = 0; li < LB; li++) {
            int cb = li * (THREADS * 16) + wid * 1024;
            int bo = cb + lane * 16;
            int row = bo >> 7;
            int coff = (bo & 127) ^ ((row & 7) << 4);
            GLOAD_LDS16(Bt + (size_t)(bcol + row) * K + kt * 64 + (coff >> 1),
                        (char*)&sB[b][0] + cb);
        }
    };

    f32x4 acc[MR][NR];
    #pragma unroll
    for (int m = 0; m < MR; m++)
        #pragma unroll
        for (int n = 0; n < NR; n++) acc[m][n] = (f32x4){0.f, 0.f, 0.f, 0.f};

    stage(0, 0);
    stage(1, 1);

    for (int kt = 0; kt < NT; kt++) {
        if (kt + 1 < NT) {
            if (LA + LB == 8) { WAIT_VM_N(8); } else { WAIT_VM_N(7); }
        } else {
            WAIT_VM_N(0);
        }
        BARRIER_RAW();                       // all waves' kt tile resident
        const char* cA = (const char*)&sA[kt & 1][0];
        const char* cB = (const char*)&sB[kt & 1][0];
        bf16x8 av[MR][2];
        #pragma unroll
        for (int m = 0; m < MR; m++)
            #pragma unroll
            for (int kc = 0; kc < 2; kc++) {
                int row = wm * (MR * 16) + m * 16 + r16;
                int byo = (row * 128 + kc * 64 + g * 16) ^ ((row & 7) << 4);
                av[m][kc] = *(const bf16x8*)(cA + byo);
            }
        #pragma unroll
        for (int n = 0; n < NR; n++) {
            bf16x8 bv[2];
            #pragma unroll
            for (int kc = 0; kc < 2; kc++) {
                int row = wn * (NR * 16) + n * 16 + r16;
                int byo = (row * 128 + kc * 64 + g * 16) ^ ((row & 7) << 4);
                bv[kc] = *(const bf16x8*)(cB + byo);
            }
            __builtin_amdgcn_s_setprio(1);
            #pragma unroll
            for (int m = 0; m < MR; m++)
                #pragma unroll
                for (int kc = 0; kc < 2; kc++)
                    acc[m][n] = __builtin_amdgcn_mfma_f32_16x16x32_bf16(av[m][kc], bv[kc], acc[m][n], 0, 0, 0);
            __builtin_amdgcn_s_setprio(0);
        }
        BARRIER_RAW();                       // all waves done reading buf[kt&1]
        if (kt + 2 < NT) stage(kt + 2, kt & 1);
        SYNC_FENCE();
    }

    #pragma unroll
    for (int m = 0; m < MR; m++) {
        #pragma unroll
        for (int n = 0; n < NR; n++) {
            int row0 = brow + wm * (MR * 16) + m * 16 + g * 4;
            int col = bcol + wn * (NR * 16) + n * 16 + r16;
            #pragma unroll
            for (int r = 0; r < 4; r++) {
                if (BF16OUT)
                    outb[(size_t)(row0 + r) * N + col] = f2bf(acc[m][n][r]);
                else
                    outf[(size_t)(row0 + r) * N + col] = acc[m][n][r];
            }
        }
    }
}

// ---------------- Flash attention: causal, GQA 4:1, hd=64 ----------------
// 64-row q-tiles, fold-pair {qp, 31-qp}, 4 blocks/CU. Q rope (+SCL) applied
// in-register at Q-fragment load (pairs (p,p+32) are lane-local across qf[0]/qf[1]).
// No-max softmax (P = exp2(s) directly), per-lane denominator partials.
// Double-buffered K/V staging; s_setprio(1) around MFMA clusters (T5).
__device__ __forceinline__ void flash_step(
    const bf16x8 (&qf)[2], float (&pl)[4], f32x4 (&oo)[4],
    const unsigned short* __restrict__ sK, const unsigned short* __restrict__ sVt,
    unsigned short* __restrict__ sPw, int g, int r16, int wid, bool masked) {
    f32x4 s[4];
    __builtin_amdgcn_s_setprio(1);
    #pragma unroll
    for (int n = 0; n < 4; n++) {
        s[n] = (f32x4){0.f, 0.f, 0.f, 0.f};
        #pragma unroll
        for (int kc = 0; kc < 2; kc++) {
            int kv = n * 16 + r16;
            int bo = (kv * 128 + kc * 64 + g * 16) ^ ((kv & 7) << 4);
            bf16x8 kf = *(const bf16x8*)((const char*)sK + bo);
            s[n] = __builtin_amdgcn_mfma_f32_16x16x32_bf16(qf[kc], kf, s[n], 0, 0, 0);
        }
    }
    __builtin_amdgcn_s_setprio(0);
    if (masked) {
        #pragma unroll
        for (int n = 0; n < 4; n++)
            #pragma unroll
            for (int r = 0; r < 4; r++)
                s[n][r] = (n * 16 + r16 <= wid * 16 + g * 4 + r) ? s[n][r] : -1e30f;
    }
    #pragma unroll
    for (int n = 0; n < 4; n++)
        #pragma unroll
        for (int r = 0; r < 4; r++) s[n][r] = exp2f(s[n][r]);
    #pragma unroll
    for (int r = 0; r < 4; r++)
        pl[r] += (s[0][r] + s[1][r]) + (s[2][r] + s[3][r]);
    #pragma unroll
    for (int n = 0; n < 4; n++)
        #pragma unroll
        for (int r = 0; r < 4; r++) {
            int prow = g * 4 + r;
            int bo = (prow * 128 + (n * 16 + r16) * 2) ^ ((prow & 7) << 4);
            union { float f; unsigned u; } pv; pv.f = s[n][r];
            *(unsigned short*)((char*)sPw + bo) = (unsigned short)(pv.u >> 16);
        }
    __builtin_amdgcn_s_setprio(1);
    #pragma unroll
    for (int dt = 0; dt < 4; dt++) {
        #pragma unroll
        for (int kc = 0; kc < 2; kc++) {
            int bo = (r16 * 128 + kc * 64 + g * 16) ^ ((r16 & 7) << 4);
            bf16x8 pf = *(const bf16x8*)((const char*)sPw + bo);
            int dd = dt * 16 + r16;
            int bo2 = (dd * 128 + kc * 64 + g * 16) ^ ((dd & 7) << 4);
            bf16x8 vf = *(const bf16x8*)((const char*)sVt + bo2);
            oo[dt] = __builtin_amdgcn_mfma_f32_16x16x32_bf16(pf, vf, oo[dt], 0, 0, 0);
        }
    }
    __builtin_amdgcn_s_setprio(0);
}

__global__ __launch_bounds__(256, 4) void attn_fwd(
    const unsigned short* __restrict__ qkv, const unsigned short* __restrict__ vt,
    unsigned short* __restrict__ att,
    const float* __restrict__ ct, const float* __restrict__ st) {
    __shared__ unsigned short sK[2][64 * 64];
    __shared__ unsigned short sVt[2][64 * 64];
    __shared__ unsigned short sP[4][16 * 64];

    int tid = threadIdx.x;
    int wid = tid >> 6, lane = tid & 63;
    int g = lane >> 4, r16 = lane & 15;
    int qp = blockIdx.x;
    int bh = blockIdx.y;
    int b = bh >> 5, qh = bh & 31, kvh = qh >> 2;
    int qtA = qp, qtB = 31 - qp;

    const unsigned short* base = qkv + (size_t)b * Tn * NQKV;
    const unsigned short* kg = base + KOFF + kvh * 64;
    const unsigned short* vg = vt + (size_t)((b * 8 + kvh) * 64) * Tn;

    // Q fragments + in-register rope (+SCL). qf[0][e] = col g*8+e (p<32),
    // qf[1][e] = col 32+g*8+e — the rotation pair is lane-local.
    bf16x8 qfA[2], qfB[2];
    int qrA = qtA * 64 + wid * 16 + r16;
    int qrB = qtB * 64 + wid * 16 + r16;
    #pragma unroll
    for (int kc = 0; kc < 2; kc++) {
        qfA[kc] = *(const bf16x8*)(base + (size_t)qrA * NQKV + qh * 64 + kc * 32 + g * 8);
        qfB[kc] = *(const bf16x8*)(base + (size_t)qrB * NQKV + qh * 64 + kc * 32 + g * 8);
    }
    #pragma unroll
    for (int e = 0; e < 8; e++) {
        int p = g * 8 + e;
        float cA = ct[qrA * 32 + p], sA_ = st[qrA * 32 + p];
        float a0 = bf2f((unsigned short)qfA[0][e]), a1 = bf2f((unsigned short)qfA[1][e]);
        qfA[0][e] = (short)f2bf((a0 * cA - a1 * sA_) * SCL);
        qfA[1][e] = (short)f2bf((a1 * cA + a0 * sA_) * SCL);
        float cB = ct[qrB * 32 + p], sB_ = st[qrB * 32 + p];
        float b0 = bf2f((unsigned short)qfB[0][e]), b1 = bf2f((unsigned short)qfB[1][e]);
        qfB[0][e] = (short)f2bf((b0 * cB - b1 * sB_) * SCL);
        qfB[1][e] = (short)f2bf((b1 * cB + b0 * sB_) * SCL);
    }

    float plA[4], plB[4];
    f32x4 oA[4], oB[4];
    #pragma unroll
    for (int r = 0; r < 4; r++) { plA[r] = 0.f; plB[r] = 0.f; }
    #pragma unroll
    for (int d = 0; d < 4; d++) {
        oA[d] = (f32x4){0.f, 0.f, 0.f, 0.f};
        oB[d] = (f32x4){0.f, 0.f, 0.f, 0.f};
    }

    unsigned short* sPw = &sP[wid][0];

    #pragma unroll
    for (int jj = 0; jj < 2; jj++) {
        int c = wid * 2 + jj;
        int bo = c * 1024 + lane * 16;
        int row = bo >> 7;
        int coff = (bo & 127) ^ ((row & 7) << 4);
        GLOAD_LDS16(kg + (size_t)row * NQKV + (coff >> 1), (char*)&sK[0][0] + c * 1024);
        GLOAD_LDS16(vg + (size_t)row * Tn + (coff >> 1), (char*)&sVt[0][0] + c * 1024);
    }
    __syncthreads();

    int cur = 0;
    for (int j = 0; j <= qtB; j++) {
        if (j < qtB) {
            int nxt = cur ^ 1;
            #pragma unroll
            for (int jj = 0; jj < 2; jj++) {
                int c = wid * 2 + jj;
                int bo = c * 1024 + lane * 16;
                int row = bo >> 7;
                int coff = (bo & 127) ^ ((row & 7) << 4);
                GLOAD_LDS16(kg + (size_t)((j + 1) * 64 + row) * NQKV + (coff >> 1),
                            (char*)&sK[nxt][0] + c * 1024);
                GLOAD_LDS16(vg + (size_t)row * Tn + (j + 1) * 64 + (coff >> 1),
                            (char*)&sVt[nxt][0] + c * 1024);
            }
        }
        const unsigned short* sKc = &sK[cur][0];
        const unsigned short* sVc = &sVt[cur][0];
        if (j <= qtA) flash_step(qfA, plA, oA, sKc, sVc, sPw, g, r16, wid, j == qtA);
        flash_step(qfB, plB, oB, sKc, sVc, sPw, g, r16, wid, j == qtB);
        __syncthreads();
        cur ^= 1;
    }

    float lA[4], lB[4];
    #pragma unroll
    for (int r = 0; r < 4; r++) {
        float vA = plA[r], vB = plB[r];
        #pragma unroll
        for (int msk = 1; msk < 16; msk <<= 1) {
            vA += __shfl_xor(vA, msk, 64);
            vB += __shfl_xor(vB, msk, 64);
        }
        lA[r] = 1.0f / vA;
        lB[r] = 1.0f / vB;
    }
    #pragma unroll
    for (int dt = 0; dt < 4; dt++)
        #pragma unroll
        for (int r = 0; r < 4; r++) {
            int qgA = qtA * 64 + wid * 16 + g * 4 + r;
            int qgB = qtB * 64 + wid * 16 + g * 4 + r;
            att[(size_t)(b * Tn + qgA) * Cn + qh * 64 + dt * 16 + r16] = f2bf(oA[dt][r] * lA[r]);
            att[(size_t)(b * Tn + qgB) * Cn + qh * 64 + dt * 16 + r16] = f2bf(oB[dt][r] * lB[r]);
        }
}

// ---------------- launch ----------------
extern "C" void kernel_launch(void* const* d_in, const int* in_sizes, int n_in,
                              void* d_out, int out_size, void* d_ws, size_t ws_size,
                              hipStream_t stream) {
    const float* x  = (const float*)d_in[0];
    const float* Wq = (const float*)d_in[1];
    const float* Wk = (const float*)d_in[2];
    const float* Wv = (const float*)d_in[3];
    const float* Wo = (const float*)d_in[4];
    float* out = (float*)d_out;

    char* w = (char*)d_ws;
    unsigned short* Xb    = (unsigned short*)w; w += (size_t)Mn * Cn * 2;       // 16.8 MB
    unsigned short* Wqkvt = (unsigned short*)w; w += (size_t)NQKV * Cn * 2;     // 12.6 MB
    unsigned short* Wot   = (unsigned short*)w; w += (size_t)Cn * Cn * 2;       //  8.4 MB
    unsigned short* QKV   = (unsigned short*)w; w += (size_t)Mn * NQKV * 2;     // 25.2 MB
    unsigned short* ATT   = (unsigned short*)w; w += (size_t)Mn * Cn * 2;       // 16.8 MB
    unsigned short* Vt    = (unsigned short*)w; w += (size_t)Bn * NKVH * HDIM * Tn * 2;  // 4.2 MB
    float* ct = (float*)w; w += (size_t)Tn * 32 * 4;
    float* st = (float*)w; w += (size_t)Tn * 32 * 4;                            // total ~84.5 MB

    convert_f32_bf16<<<(Mn * Cn / 4) / 256, 256, 0, stream>>>(x, Xb, Mn * Cn / 4);
    dim3 tb(32, 8);
    transpose_wqkv<<<dim3(64, 96), tb, 0, stream>>>(Wq, Wk, Wv, Wqkvt);
    transpose_convert<<<dim3(64, 64), tb, 0, stream>>>(Wo, Wot, Cn, 2048);
    rope_tables<<<(Tn * 32) / 256, 256, 0, stream>>>(ct, st);

    // QKV GEMM: 256x192 tiles -> grid 16x16 = 256 blocks = exact CU fill.
    gemm_pipe<256, 192, 2, 4, true, false><<<dim3(NQKV / 192, Mn / 256), 512, 0, stream>>>(
        Xb, Wqkvt, QKV, nullptr, NQKV, Cn);
    rope_k<<<(Mn * 8 * 32) / 256, 256, 0, stream>>>(QKV, ct, st);
    transpose_v<<<dim3(Tn / 32, Bn * NKVH, 2), tb, 0, stream>>>(QKV, Vt);
    attn_fwd<<<dim3(16, Bn * NHEAD), 256, 0, stream>>>(QKV, Vt, ATT, ct, st);
    gemm_pipe<128, 128, 2, 2, false, false><<<dim3(Cn / 128, Mn / 128), 256, 0, stream>>>(
        ATT, Wot, nullptr, out, Cn, Cn);
}

// Round 27
// 213.451 us; speedup vs baseline: 1.0018x; 1.0018x over previous
//
#include <hip/hip_runtime.h>
#include <stdint.h>

#define Bn 2
#define Tn 2048
#define Cn 2048
#define NHEAD 32
#define NKVH 8
#define HDIM 64
#define Mn (Bn*Tn)        // 4096
#define NQKV 3072         // 2048 Q | 512 K | 512 V
#define KOFF 2048
#define VOFF 2560

typedef __attribute__((ext_vector_type(8))) short bf16x8;
typedef __attribute__((ext_vector_type(4))) float f32x4;

#define AS1 __attribute__((address_space(1)))
#define AS3 __attribute__((address_space(3)))
#define GLOAD_LDS16(g, l) __builtin_amdgcn_global_load_lds((const AS1 void*)(g), (AS3 void*)(l), 16, 0, 0)

#define SCL 0.18033688f  /* 0.125 * log2(e) — folded into Q during attn's in-register rope */

#define SYNC_FENCE() __builtin_amdgcn_sched_barrier(0)
#define WAIT_VM_N(N_) do { asm volatile("s_waitcnt vmcnt(" #N_ ")" ::: "memory"); SYNC_FENCE(); } while (0)
#define BARRIER_RAW() do { __builtin_amdgcn_s_barrier(); SYNC_FENCE(); } while (0)

__device__ __forceinline__ unsigned short f2bf(float f) {
    union { float f; unsigned u; } v; v.f = f;
    return (unsigned short)((v.u + 0x7fffu + ((v.u >> 16) & 1u)) >> 16);
}
__device__ __forceinline__ float bf2f(unsigned short b) {
    union { unsigned u; float f; } v; v.u = ((unsigned)b) << 16;
    return v.f;
}

// ---------------- elementwise fp32 -> bf16 (vectorized) ----------------
__global__ void convert_f32_bf16(const float* __restrict__ src,
                                 unsigned short* __restrict__ dst, int n4) {
    int i = blockIdx.x * blockDim.x + threadIdx.x;
    if (i >= n4) return;
    float4 f = ((const float4*)src)[i];
    ushort4 o;
    o.x = f2bf(f.x); o.y = f2bf(f.y); o.z = f2bf(f.z); o.w = f2bf(f.w);
    ((ushort4*)dst)[i] = o;
}

// ---------------- transpose + convert: src (K x N) fp32 -> dst (N x K) bf16 ----------------
__global__ void transpose_convert(const float* __restrict__ src,
                                  unsigned short* __restrict__ dst, int K, int N) {
    __shared__ float tile[32][33];
    int k0 = blockIdx.x * 32, n0 = blockIdx.y * 32;
    int tx = threadIdx.x, ty = threadIdx.y;  // 32 x 8
    #pragma unroll
    for (int yy = 0; yy < 32; yy += 8)
        tile[ty + yy][tx] = src[(size_t)(k0 + ty + yy) * N + n0 + tx];
    __syncthreads();
    #pragma unroll
    for (int yy = 0; yy < 32; yy += 8)
        dst[(size_t)(n0 + ty + yy) * K + k0 + tx] = f2bf(tile[tx][ty + yy]);
}

// ---------------- merged Wq|Wk|Wv transpose -> Wqkvt[3072][2048] ----------------
__global__ void transpose_wqkv(const float* __restrict__ Wq, const float* __restrict__ Wk,
                               const float* __restrict__ Wv, unsigned short* __restrict__ dst) {
    __shared__ float tile[32][33];
    int k0 = blockIdx.x * 32, n0 = blockIdx.y * 32;  // n0 in [0,3072)
    const float* src; int srcN, c0;
    if (n0 < 2048)      { src = Wq; srcN = 2048; c0 = n0; }
    else if (n0 < 2560) { src = Wk; srcN = 512;  c0 = n0 - 2048; }
    else                { src = Wv; srcN = 512;  c0 = n0 - 2560; }
    int tx = threadIdx.x, ty = threadIdx.y;  // 32 x 8
    #pragma unroll
    for (int yy = 0; yy < 32; yy += 8)
        tile[ty + yy][tx] = src[(size_t)(k0 + ty + yy) * srcN + c0 + tx];
    __syncthreads();
    #pragma unroll
    for (int yy = 0; yy < 32; yy += 8)
        dst[(size_t)(n0 + ty + yy) * Cn + k0 + tx] = f2bf(tile[tx][ty + yy]);
}

// ---------------- RoPE tables: ct/st [Tn][32] fp32 ----------------
__global__ void rope_tables(float* __restrict__ ct, float* __restrict__ st) {
    int i = blockIdx.x * blockDim.x + threadIdx.x;  // Tn*32
    int t = i >> 5, d = i & 31;
    float invf = powf(10000.0f, -(float)d / 32.0f);
    float f = (float)t * invf;
    ct[i] = cosf(f);
    st[i] = sinf(f);
}

// ---------------- RoPE in-place on K heads only (no scale) ----------------
__global__ void rope_k(unsigned short* __restrict__ qkv,
                       const float* __restrict__ ct, const float* __restrict__ st) {
    int i = blockIdx.x * blockDim.x + threadIdx.x;  // Mn * 8 * 32
    int p = i & 31;
    int kvh = (i >> 5) & 7;
    int bt = i >> 8;
    int t = bt & (Tn - 1);
    size_t base = (size_t)bt * NQKV + KOFF + kvh * 64;
    float v0 = bf2f(qkv[base + p]);
    float v1 = bf2f(qkv[base + p + 32]);
    float c = ct[t * 32 + p], s = st[t * 32 + p];
    qkv[base + p]      = f2bf(v0 * c - v1 * s);
    qkv[base + p + 32] = f2bf(v1 * c + v0 * s);
}

// ---------------- V transpose: QKV V-part -> Vt[b][kvh][d][t] (bf16) ----------------
__global__ void transpose_v(const unsigned short* __restrict__ qkv,
                            unsigned short* __restrict__ vt) {
    __shared__ unsigned short tile[32][33];
    int t0 = blockIdx.x * 32;
    int b = blockIdx.y >> 3, kvh = blockIdx.y & 7;
    int d0 = blockIdx.z * 32;
    int tx = threadIdx.x, ty = threadIdx.y;  // 32 x 8
    #pragma unroll
    for (int yy = 0; yy < 32; yy += 8)
        tile[ty + yy][tx] = qkv[(size_t)(b * Tn + t0 + ty + yy) * NQKV + VOFF + kvh * 64 + d0 + tx];
    __syncthreads();
    #pragma unroll
    for (int yy = 0; yy < 32; yy += 8)
        vt[(size_t)((b * 8 + kvh) * 64 + d0 + ty + yy) * Tn + t0 + tx] = tile[tx][ty + yy];
}

// ---------------- Pipelined GEMM template: C = A[M,K] @ Bt[N,K]^T ----------------
// BK=64, double-buffered LDS, counted-vmcnt schedule (loads never drained to 0
// in the main loop), raw barriers. BF16OUT selects output dtype.
template <int BM, int BN, int WMv, int WNv, bool BF16OUT, bool SWZ>
__global__ __launch_bounds__(WMv * WNv * 64, 2) void gemm_pipe(
    const unsigned short* __restrict__ A, const unsigned short* __restrict__ Bt,
    unsigned short* __restrict__ outb, float* __restrict__ outf, int N, int K) {
    constexpr int THREADS = WMv * WNv * 64;
    constexpr int MR = BM / WMv / 16;           // m-frags per wave
    constexpr int NR = BN / WNv / 16;           // n-frags per wave
    constexpr int LA = (BM * 64 * 2) / (THREADS * 16);  // A gload_lds per thread
    constexpr int LB = (BN * 64 * 2) / (THREADS * 16);  // B gload_lds per thread

    __shared__ unsigned short sA[2][BM * 64];
    __shared__ unsigned short sB[2][BN * 64];

    int tid = threadIdx.x;
    int wid = tid >> 6, lane = tid & 63;
    int wm = wid / WNv, wn = wid % WNv;
    int g = lane >> 4, r16 = lane & 15;

    int bx, by;
    if (SWZ) {
        int nwg = gridDim.x * gridDim.y;
        int lid = blockIdx.y * gridDim.x + blockIdx.x;
        int swz = (lid & 7) * (nwg >> 3) + (lid >> 3);
        bx = swz % gridDim.x; by = swz / gridDim.x;
    } else {
        bx = blockIdx.x; by = blockIdx.y;
    }
    int brow = by * BM, bcol = bx * BN;

    int NT = K / 64;

    auto stage = [&](int kt, int b) {
        #pragma unroll
        for (int li = 0; li < LA; li++) {
            int cb = li * (THREADS * 16) + wid * 1024;
            int bo = cb + lane * 16;
            int row = bo >> 7;
            int coff = (bo & 127) ^ ((row & 7) << 4);
            GLOAD_LDS16(A + (size_t)(brow + row) * K + kt * 64 + (coff >> 1),
                        (char*)&sA[b][0] + cb);
        }
        #pragma unroll
        for (int li = 0; li < LB; li++) {
            int cb = li * (THREADS * 16) + wid * 1024;
            int bo = cb + lane * 16;
            int row = bo >> 7;
            int coff = (bo & 127) ^ ((row & 7) << 4);
            GLOAD_LDS16(Bt + (size_t)(bcol + row) * K + kt * 64 + (coff >> 1),
                        (char*)&sB[b][0] + cb);
        }
    };

    f32x4 acc[MR][NR];
    #pragma unroll
    for (int m = 0; m < MR; m++)
        #pragma unroll
        for (int n = 0; n < NR; n++) acc[m][n] = (f32x4){0.f, 0.f, 0.f, 0.f};

    stage(0, 0);
    stage(1, 1);

    for (int kt = 0; kt < NT; kt++) {
        if (kt + 1 < NT) {
            if (LA + LB == 8) { WAIT_VM_N(8); } else { WAIT_VM_N(7); }
        } else {
            WAIT_VM_N(0);
        }
        BARRIER_RAW();                       // all waves' kt tile resident
        const char* cA = (const char*)&sA[kt & 1][0];
        const char* cB = (const char*)&sB[kt & 1][0];
        bf16x8 av[MR][2];
        #pragma unroll
        for (int m = 0; m < MR; m++)
            #pragma unroll
            for (int kc = 0; kc < 2; kc++) {
                int row = wm * (MR * 16) + m * 16 + r16;
                int byo = (row * 128 + kc * 64 + g * 16) ^ ((row & 7) << 4);
                av[m][kc] = *(const bf16x8*)(cA + byo);
            }
        #pragma unroll
        for (int n = 0; n < NR; n++) {
            bf16x8 bv[2];
            #pragma unroll
            for (int kc = 0; kc < 2; kc++) {
                int row = wn * (NR * 16) + n * 16 + r16;
                int byo = (row * 128 + kc * 64 + g * 16) ^ ((row & 7) << 4);
                bv[kc] = *(const bf16x8*)(cB + byo);
            }
            __builtin_amdgcn_s_setprio(1);
            #pragma unroll
            for (int m = 0; m < MR; m++)
                #pragma unroll
                for (int kc = 0; kc < 2; kc++)
                    acc[m][n] = __builtin_amdgcn_mfma_f32_16x16x32_bf16(av[m][kc], bv[kc], acc[m][n], 0, 0, 0);
            __builtin_amdgcn_s_setprio(0);
        }
        BARRIER_RAW();                       // all waves done reading buf[kt&1]
        if (kt + 2 < NT) stage(kt + 2, kt & 1);
        SYNC_FENCE();
    }

    #pragma unroll
    for (int m = 0; m < MR; m++) {
        #pragma unroll
        for (int n = 0; n < NR; n++) {
            int row0 = brow + wm * (MR * 16) + m * 16 + g * 4;
            int col = bcol + wn * (NR * 16) + n * 16 + r16;
            #pragma unroll
            for (int r = 0; r < 4; r++) {
                if (BF16OUT)
                    outb[(size_t)(row0 + r) * N + col] = f2bf(acc[m][n][r]);
                else
                    outf[(size_t)(row0 + r) * N + col] = acc[m][n][r];
            }
        }
    }
}

// ---------------- Flash attention: causal, GQA 4:1, hd=64 ----------------
// 64-row q-tiles, fold-pair {qp, 31-qp}, 4 blocks/CU. Q rope (+SCL) applied
// in-register at Q-fragment load (pairs (p,p+32) are lane-local across qf[0]/qf[1]).
// No-max softmax (P = exp2(s) directly), per-lane denominator partials.
// Double-buffered K/V staging; s_setprio(1) around MFMA clusters (T5).
__device__ __forceinline__ void flash_step(
    const bf16x8 (&qf)[2], float (&pl)[4], f32x4 (&oo)[4],
    const unsigned short* __restrict__ sK, const unsigned short* __restrict__ sVt,
    unsigned short* __restrict__ sPw, int g, int r16, int wid, bool masked) {
    f32x4 s[4];
    __builtin_amdgcn_s_setprio(1);
    #pragma unroll
    for (int n = 0; n < 4; n++) {
        s[n] = (f32x4){0.f, 0.f, 0.f, 0.f};
        #pragma unroll
        for (int kc = 0; kc < 2; kc++) {
            int kv = n * 16 + r16;
            int bo = (kv * 128 + kc * 64 + g * 16) ^ ((kv & 7) << 4);
            bf16x8 kf = *(const bf16x8*)((const char*)sK + bo);
            s[n] = __builtin_amdgcn_mfma_f32_16x16x32_bf16(qf[kc], kf, s[n], 0, 0, 0);
        }
    }
    __builtin_amdgcn_s_setprio(0);
    if (masked) {
        #pragma unroll
        for (int n = 0; n < 4; n++)
            #pragma unroll
            for (int r = 0; r < 4; r++)
                s[n][r] = (n * 16 + r16 <= wid * 16 + g * 4 + r) ? s[n][r] : -1e30f;
    }
    #pragma unroll
    for (int n = 0; n < 4; n++)
        #pragma unroll
        for (int r = 0; r < 4; r++) s[n][r] = exp2f(s[n][r]);
    #pragma unroll
    for (int r = 0; r < 4; r++)
        pl[r] += (s[0][r] + s[1][r]) + (s[2][r] + s[3][r]);
    #pragma unroll
    for (int n = 0; n < 4; n++)
        #pragma unroll
        for (int r = 0; r < 4; r++) {
            int prow = g * 4 + r;
            int bo = (prow * 128 + (n * 16 + r16) * 2) ^ ((prow & 7) << 4);
            union { float f; unsigned u; } pv; pv.f = s[n][r];
            *(unsigned short*)((char*)sPw + bo) = (unsigned short)(pv.u >> 16);
        }
    __builtin_amdgcn_s_setprio(1);
    #pragma unroll
    for (int dt = 0; dt < 4; dt++) {
        #pragma unroll
        for (int kc = 0; kc < 2; kc++) {
            int bo = (r16 * 128 + kc * 64 + g * 16) ^ ((r16 & 7) << 4);
            bf16x8 pf = *(const bf16x8*)((const char*)sPw + bo);
            int dd = dt * 16 + r16;
            int bo2 = (dd * 128 + kc * 64 + g * 16) ^ ((dd & 7) << 4);
            bf16x8 vf = *(const bf16x8*)((const char*)sVt + bo2);
            oo[dt] = __builtin_amdgcn_mfma_f32_16x16x32_bf16(pf, vf, oo[dt], 0, 0, 0);
        }
    }
    __builtin_amdgcn_s_setprio(0);
}

__global__ __launch_bounds__(256, 4) void attn_fwd(
    const unsigned short* __restrict__ qkv, const unsigned short* __restrict__ vt,
    unsigned short* __restrict__ att,
    const float* __restrict__ ct, const float* __restrict__ st) {
    __shared__ unsigned short sK[2][64 * 64];
    __shared__ unsigned short sVt[2][64 * 64];
    __shared__ unsigned short sP[4][16 * 64];

    int tid = threadIdx.x;
    int wid = tid >> 6, lane = tid & 63;
    int g = lane >> 4, r16 = lane & 15;
    int qp = blockIdx.x;
    int bh = blockIdx.y;
    int b = bh >> 5, qh = bh & 31, kvh = qh >> 2;
    int qtA = qp, qtB = 31 - qp;

    const unsigned short* base = qkv + (size_t)b * Tn * NQKV;
    const unsigned short* kg = base + KOFF + kvh * 64;
    const unsigned short* vg = vt + (size_t)((b * 8 + kvh) * 64) * Tn;

    // Q fragments + in-register rope (+SCL). qf[0][e] = col g*8+e (p<32),
    // qf[1][e] = col 32+g*8+e — the rotation pair is lane-local.
    bf16x8 qfA[2], qfB[2];
    int qrA = qtA * 64 + wid * 16 + r16;
    int qrB = qtB * 64 + wid * 16 + r16;
    #pragma unroll
    for (int kc = 0; kc < 2; kc++) {
        qfA[kc] = *(const bf16x8*)(base + (size_t)qrA * NQKV + qh * 64 + kc * 32 + g * 8);
        qfB[kc] = *(const bf16x8*)(base + (size_t)qrB * NQKV + qh * 64 + kc * 32 + g * 8);
    }
    #pragma unroll
    for (int e = 0; e < 8; e++) {
        int p = g * 8 + e;
        float cA = ct[qrA * 32 + p], sA_ = st[qrA * 32 + p];
        float a0 = bf2f((unsigned short)qfA[0][e]), a1 = bf2f((unsigned short)qfA[1][e]);
        qfA[0][e] = (short)f2bf((a0 * cA - a1 * sA_) * SCL);
        qfA[1][e] = (short)f2bf((a1 * cA + a0 * sA_) * SCL);
        float cB = ct[qrB * 32 + p], sB_ = st[qrB * 32 + p];
        float b0 = bf2f((unsigned short)qfB[0][e]), b1 = bf2f((unsigned short)qfB[1][e]);
        qfB[0][e] = (short)f2bf((b0 * cB - b1 * sB_) * SCL);
        qfB[1][e] = (short)f2bf((b1 * cB + b0 * sB_) * SCL);
    }

    float plA[4], plB[4];
    f32x4 oA[4], oB[4];
    #pragma unroll
    for (int r = 0; r < 4; r++) { plA[r] = 0.f; plB[r] = 0.f; }
    #pragma unroll
    for (int d = 0; d < 4; d++) {
        oA[d] = (f32x4){0.f, 0.f, 0.f, 0.f};
        oB[d] = (f32x4){0.f, 0.f, 0.f, 0.f};
    }

    unsigned short* sPw = &sP[wid][0];

    #pragma unroll
    for (int jj = 0; jj < 2; jj++) {
        int c = wid * 2 + jj;
        int bo = c * 1024 + lane * 16;
        int row = bo >> 7;
        int coff = (bo & 127) ^ ((row & 7) << 4);
        GLOAD_LDS16(kg + (size_t)row * NQKV + (coff >> 1), (char*)&sK[0][0] + c * 1024);
        GLOAD_LDS16(vg + (size_t)row * Tn + (coff >> 1), (char*)&sVt[0][0] + c * 1024);
    }
    __syncthreads();

    int cur = 0;
    for (int j = 0; j <= qtB; j++) {
        if (j < qtB) {
            int nxt = cur ^ 1;
            #pragma unroll
            for (int jj = 0; jj < 2; jj++) {
                int c = wid * 2 + jj;
                int bo = c * 1024 + lane * 16;
                int row = bo >> 7;
                int coff = (bo & 127) ^ ((row & 7) << 4);
                GLOAD_LDS16(kg + (size_t)((j + 1) * 64 + row) * NQKV + (coff >> 1),
                            (char*)&sK[nxt][0] + c * 1024);
                GLOAD_LDS16(vg + (size_t)row * Tn + (j + 1) * 64 + (coff >> 1),
                            (char*)&sVt[nxt][0] + c * 1024);
            }
        }
        const unsigned short* sKc = &sK[cur][0];
        const unsigned short* sVc = &sVt[cur][0];
        if (j <= qtA) flash_step(qfA, plA, oA, sKc, sVc, sPw, g, r16, wid, j == qtA);
        flash_step(qfB, plB, oB, sKc, sVc, sPw, g, r16, wid, j == qtB);
        __syncthreads();
        cur ^= 1;
    }

    float lA[4], lB[4];
    #pragma unroll
    for (int r = 0; r < 4; r++) {
        float vA = plA[r], vB = plB[r];
        #pragma unroll
        for (int msk = 1; msk < 16; msk <<= 1) {
            vA += __shfl_xor(vA, msk, 64);
            vB += __shfl_xor(vB, msk, 64);
        }
        lA[r] = 1.0f / vA;
        lB[r] = 1.0f / vB;
    }
    #pragma unroll
    for (int dt = 0; dt < 4; dt++)
        #pragma unroll
        for (int r = 0; r < 4; r++) {
            int qgA = qtA * 64 + wid * 16 + g * 4 + r;
            int qgB = qtB * 64 + wid * 16 + g * 4 + r;
            att[(size_t)(b * Tn + qgA) * Cn + qh * 64 + dt * 16 + r16] = f2bf(oA[dt][r] * lA[r]);
            att[(size_t)(b * Tn + qgB) * Cn + qh * 64 + dt * 16 + r16] = f2bf(oB[dt][r] * lB[r]);
        }
}

// ---------------- launch ----------------
extern "C" void kernel_launch(void* const* d_in, const int* in_sizes, int n_in,
                              void* d_out, int out_size, void* d_ws, size_t ws_size,
                              hipStream_t stream) {
    const float* x  = (const float*)d_in[0];
    const float* Wq = (const float*)d_in[1];
    const float* Wk = (const float*)d_in[2];
    const float* Wv = (const float*)d_in[3];
    const float* Wo = (const float*)d_in[4];
    float* out = (float*)d_out;

    char* w = (char*)d_ws;
    unsigned short* Xb    = (unsigned short*)w; w += (size_t)Mn * Cn * 2;       // 16.8 MB
    unsigned short* Wqkvt = (unsigned short*)w; w += (size_t)NQKV * Cn * 2;     // 12.6 MB
    unsigned short* Wot   = (unsigned short*)w; w += (size_t)Cn * Cn * 2;       //  8.4 MB
    unsigned short* QKV   = (unsigned short*)w; w += (size_t)Mn * NQKV * 2;     // 25.2 MB
    unsigned short* ATT   = (unsigned short*)w; w += (size_t)Mn * Cn * 2;       // 16.8 MB
    unsigned short* Vt    = (unsigned short*)w; w += (size_t)Bn * NKVH * HDIM * Tn * 2;  // 4.2 MB
    float* ct = (float*)w; w += (size_t)Tn * 32 * 4;
    float* st = (float*)w; w += (size_t)Tn * 32 * 4;                            // total ~84.5 MB

    convert_f32_bf16<<<(Mn * Cn / 4) / 256, 256, 0, stream>>>(x, Xb, Mn * Cn / 4);
    dim3 tb(32, 8);
    transpose_wqkv<<<dim3(64, 96), tb, 0, stream>>>(Wq, Wk, Wv, Wqkvt);
    transpose_convert<<<dim3(64, 64), tb, 0, stream>>>(Wo, Wot, Cn, 2048);
    rope_tables<<<(Tn * 32) / 256, 256, 0, stream>>>(ct, st);

    // QKV GEMM: 256x192 tiles -> grid 16x16 = 256 blocks = exact CU fill.
    gemm_pipe<256, 192, 2, 4, true, false><<<dim3(NQKV / 192, Mn / 256), 512, 0, stream>>>(
        Xb, Wqkvt, QKV, nullptr, NQKV, Cn);
    rope_k<<<(Mn * 8 * 32) / 256, 256, 0, stream>>>(QKV, ct, st);
    transpose_v<<<dim3(Tn / 32, Bn * NKVH, 2), tb, 0, stream>>>(QKV, Vt);
    attn_fwd<<<dim3(16, Bn * NHEAD), 256, 0, stream>>>(QKV, Vt, ATT, ct, st);
    gemm_pipe<128, 128, 2, 2, false, false><<<dim3(Cn / 128, Mn / 128), 256, 0, stream>>>(
        ATT, Wot, nullptr, out, Cn, Cn);
}

// Round 28
// 213.437 us; speedup vs baseline: 1.0019x; 1.0001x over previous
//
#include <hip/hip_runtime.h>
#include <stdint.h>

#define Bn 2
#define Tn 2048
#define Cn 2048
#define NHEAD 32
#define NKVH 8
#define HDIM 64
#define Mn (Bn*Tn)        // 4096
#define NQKV 3072         // 2048 Q | 512 K | 512 V
#define KOFF 2048
#define VOFF 2560

typedef __attribute__((ext_vector_type(8))) short bf16x8;
typedef __attribute__((ext_vector_type(4))) float f32x4;

#define AS1 __attribute__((address_space(1)))
#define AS3 __attribute__((address_space(3)))
#define GLOAD_LDS16(g, l) __builtin_amdgcn_global_load_lds((const AS1 void*)(g), (AS3 void*)(l), 16, 0, 0)

#define SCL 0.18033688f  /* 0.125 * log2(e) — folded into Q during attn's in-register rope */

#define SYNC_FENCE() __builtin_amdgcn_sched_barrier(0)
#define WAIT_VM_N(N_) do { asm volatile("s_waitcnt vmcnt(" #N_ ")" ::: "memory"); SYNC_FENCE(); } while (0)
#define BARRIER_RAW() do { __builtin_amdgcn_s_barrier(); SYNC_FENCE(); } while (0)

__device__ __forceinline__ unsigned short f2bf(float f) {
    union { float f; unsigned u; } v; v.f = f;
    return (unsigned short)((v.u + 0x7fffu + ((v.u >> 16) & 1u)) >> 16);
}
__device__ __forceinline__ float bf2f(unsigned short b) {
    union { unsigned u; float f; } v; v.u = ((unsigned)b) << 16;
    return v.f;
}

// ---------------- elementwise fp32 -> bf16 (vectorized) ----------------
__global__ void convert_f32_bf16(const float* __restrict__ src,
                                 unsigned short* __restrict__ dst, int n4) {
    int i = blockIdx.x * blockDim.x + threadIdx.x;
    if (i >= n4) return;
    float4 f = ((const float4*)src)[i];
    ushort4 o;
    o.x = f2bf(f.x); o.y = f2bf(f.y); o.z = f2bf(f.z); o.w = f2bf(f.w);
    ((ushort4*)dst)[i] = o;
}

// ---------------- transpose + convert: src (K x N) fp32 -> dst (N x K) bf16 ----------------
__global__ void transpose_convert(const float* __restrict__ src,
                                  unsigned short* __restrict__ dst, int K, int N) {
    __shared__ float tile[32][33];
    int k0 = blockIdx.x * 32, n0 = blockIdx.y * 32;
    int tx = threadIdx.x, ty = threadIdx.y;  // 32 x 8
    #pragma unroll
    for (int yy = 0; yy < 32; yy += 8)
        tile[ty + yy][tx] = src[(size_t)(k0 + ty + yy) * N + n0 + tx];
    __syncthreads();
    #pragma unroll
    for (int yy = 0; yy < 32; yy += 8)
        dst[(size_t)(n0 + ty + yy) * K + k0 + tx] = f2bf(tile[tx][ty + yy]);
}

// ---------------- merged Wq|Wk|Wv transpose -> Wqkvt[3072][2048] ----------------
__global__ void transpose_wqkv(const float* __restrict__ Wq, const float* __restrict__ Wk,
                               const float* __restrict__ Wv, unsigned short* __restrict__ dst) {
    __shared__ float tile[32][33];
    int k0 = blockIdx.x * 32, n0 = blockIdx.y * 32;  // n0 in [0,3072)
    const float* src; int srcN, c0;
    if (n0 < 2048)      { src = Wq; srcN = 2048; c0 = n0; }
    else if (n0 < 2560) { src = Wk; srcN = 512;  c0 = n0 - 2048; }
    else                { src = Wv; srcN = 512;  c0 = n0 - 2560; }
    int tx = threadIdx.x, ty = threadIdx.y;  // 32 x 8
    #pragma unroll
    for (int yy = 0; yy < 32; yy += 8)
        tile[ty + yy][tx] = src[(size_t)(k0 + ty + yy) * srcN + c0 + tx];
    __syncthreads();
    #pragma unroll
    for (int yy = 0; yy < 32; yy += 8)
        dst[(size_t)(n0 + ty + yy) * Cn + k0 + tx] = f2bf(tile[tx][ty + yy]);
}

// ---------------- RoPE tables: ct/st [Tn][32] fp32 ----------------
__global__ void rope_tables(float* __restrict__ ct, float* __restrict__ st) {
    int i = blockIdx.x * blockDim.x + threadIdx.x;  // Tn*32
    int t = i >> 5, d = i & 31;
    float invf = powf(10000.0f, -(float)d / 32.0f);
    float f = (float)t * invf;
    ct[i] = cosf(f);
    st[i] = sinf(f);
}

// ---------------- RoPE in-place on K heads only (no scale) ----------------
__global__ void rope_k(unsigned short* __restrict__ qkv,
                       const float* __restrict__ ct, const float* __restrict__ st) {
    int i = blockIdx.x * blockDim.x + threadIdx.x;  // Mn * 8 * 32
    int p = i & 31;
    int kvh = (i >> 5) & 7;
    int bt = i >> 8;
    int t = bt & (Tn - 1);
    size_t base = (size_t)bt * NQKV + KOFF + kvh * 64;
    float v0 = bf2f(qkv[base + p]);
    float v1 = bf2f(qkv[base + p + 32]);
    float c = ct[t * 32 + p], s = st[t * 32 + p];
    qkv[base + p]      = f2bf(v0 * c - v1 * s);
    qkv[base + p + 32] = f2bf(v1 * c + v0 * s);
}

// ---------------- V transpose: QKV V-part -> Vt[b][kvh][d][t] (bf16) ----------------
__global__ void transpose_v(const unsigned short* __restrict__ qkv,
                            unsigned short* __restrict__ vt) {
    __shared__ unsigned short tile[32][33];
    int t0 = blockIdx.x * 32;
    int b = blockIdx.y >> 3, kvh = blockIdx.y & 7;
    int d0 = blockIdx.z * 32;
    int tx = threadIdx.x, ty = threadIdx.y;  // 32 x 8
    #pragma unroll
    for (int yy = 0; yy < 32; yy += 8)
        tile[ty + yy][tx] = qkv[(size_t)(b * Tn + t0 + ty + yy) * NQKV + VOFF + kvh * 64 + d0 + tx];
    __syncthreads();
    #pragma unroll
    for (int yy = 0; yy < 32; yy += 8)
        vt[(size_t)((b * 8 + kvh) * 64 + d0 + ty + yy) * Tn + t0 + tx] = tile[tx][ty + yy];
}

// ---------------- Pipelined GEMM template: C = A[M,K] @ Bt[N,K]^T ----------------
// BK=64, double-buffered LDS, counted-vmcnt schedule (loads never drained to 0
// in the main loop), raw barriers. BF16OUT selects output dtype.
template <int BM, int BN, int WMv, int WNv, bool BF16OUT, bool SWZ>
__global__ __launch_bounds__(WMv * WNv * 64, 2) void gemm_pipe(
    const unsigned short* __restrict__ A, const unsigned short* __restrict__ Bt,
    unsigned short* __restrict__ outb, float* __restrict__ outf, int N, int K) {
    constexpr int THREADS = WMv * WNv * 64;
    constexpr int MR = BM / WMv / 16;           // m-frags per wave
    constexpr int NR = BN / WNv / 16;           // n-frags per wave
    constexpr int LA = (BM * 64 * 2) / (THREADS * 16);  // A gload_lds per thread
    constexpr int LB = (BN * 64 * 2) / (THREADS * 16);  // B gload_lds per thread

    __shared__ unsigned short sA[2][BM * 64];
    __shared__ unsigned short sB[2][BN * 64];

    int tid = threadIdx.x;
    int wid = tid >> 6, lane = tid & 63;
    int wm = wid / WNv, wn = wid % WNv;
    int g = lane >> 4, r16 = lane & 15;

    int bx, by;
    if (SWZ) {
        int nwg = gridDim.x * gridDim.y;
        int lid = blockIdx.y * gridDim.x + blockIdx.x;
        int swz = (lid & 7) * (nwg >> 3) + (lid >> 3);
        bx = swz % gridDim.x; by = swz / gridDim.x;
    } else {
        bx = blockIdx.x; by = blockIdx.y;
    }
    int brow = by * BM, bcol = bx * BN;

    int NT = K / 64;

    auto stage = [&](int kt, int b) {
        #pragma unroll
        for (int li = 0; li < LA; li++) {
            int cb = li * (THREADS * 16) + wid * 1024;
            int bo = cb + lane * 16;
            int row = bo >> 7;
            int coff = (bo & 127) ^ ((row & 7) << 4);
            GLOAD_LDS16(A + (size_t)(brow + row) * K + kt * 64 + (coff >> 1),
                        (char*)&sA[b][0] + cb);
        }
        #pragma unroll
        for (int li = 0; li < LB; li++) {
            int cb = li * (THREADS * 16) + wid * 1024;
            int bo = cb + lane * 16;
            int row = bo >> 7;
            int coff = (bo & 127) ^ ((row & 7) << 4);
            GLOAD_LDS16(Bt + (size_t)(bcol + row) * K + kt * 64 + (coff >> 1),
                        (char*)&sB[b][0] + cb);
        }
    };

    f32x4 acc[MR][NR];
    #pragma unroll
    for (int m = 0; m < MR; m++)
        #pragma unroll
        for (int n = 0; n < NR; n++) acc[m][n] = (f32x4){0.f, 0.f, 0.f, 0.f};

    stage(0, 0);
    stage(1, 1);

    for (int kt = 0; kt < NT; kt++) {
        if (kt + 1 < NT) {
            if (LA + LB == 8) { WAIT_VM_N(8); } else { WAIT_VM_N(7); }
        } else {
            WAIT_VM_N(0);
        }
        BARRIER_RAW();                       // all waves' kt tile resident
        const char* cA = (const char*)&sA[kt & 1][0];
        const char* cB = (const char*)&sB[kt & 1][0];
        bf16x8 av[MR][2];
        #pragma unroll
        for (int m = 0; m < MR; m++)
            #pragma unroll
            for (int kc = 0; kc < 2; kc++) {
                int row = wm * (MR * 16) + m * 16 + r16;
                int byo = (row * 128 + kc * 64 + g * 16) ^ ((row & 7) << 4);
                av[m][kc] = *(const bf16x8*)(cA + byo);
            }
        #pragma unroll
        for (int n = 0; n < NR; n++) {
            bf16x8 bv[2];
            #pragma unroll
            for (int kc = 0; kc < 2; kc++) {
                int row = wn * (NR * 16) + n * 16 + r16;
                int byo = (row * 128 + kc * 64 + g * 16) ^ ((row & 7) << 4);
                bv[kc] = *(const bf16x8*)(cB + byo);
            }
            __builtin_amdgcn_s_setprio(1);
            #pragma unroll
            for (int m = 0; m < MR; m++)
                #pragma unroll
                for (int kc = 0; kc < 2; kc++)
                    acc[m][n] = __builtin_amdgcn_mfma_f32_16x16x32_bf16(av[m][kc], bv[kc], acc[m][n], 0, 0, 0);
            __builtin_amdgcn_s_setprio(0);
        }
        BARRIER_RAW();                       // all waves done reading buf[kt&1]
        if (kt + 2 < NT) stage(kt + 2, kt & 1);
        SYNC_FENCE();
    }

    #pragma unroll
    for (int m = 0; m < MR; m++) {
        #pragma unroll
        for (int n = 0; n < NR; n++) {
            int row0 = brow + wm * (MR * 16) + m * 16 + g * 4;
            int col = bcol + wn * (NR * 16) + n * 16 + r16;
            #pragma unroll
            for (int r = 0; r < 4; r++) {
                if (BF16OUT)
                    outb[(size_t)(row0 + r) * N + col] = f2bf(acc[m][n][r]);
                else
                    outf[(size_t)(row0 + r) * N + col] = acc[m][n][r];
            }
        }
    }
}

// ---------------- Flash attention: causal, GQA 4:1, hd=64 ----------------
// 64-row q-tiles, fold-pair {qp, 31-qp}, 4 blocks/CU. Q rope (+SCL) applied
// in-register at Q-fragment load (pairs (p,p+32) are lane-local across qf[0]/qf[1]).
// No-max softmax (P = exp2(s) directly), per-lane denominator partials.
// Double-buffered K/V staging; s_setprio(1) around MFMA clusters (T5).
__device__ __forceinline__ void flash_step(
    const bf16x8 (&qf)[2], float (&pl)[4], f32x4 (&oo)[4],
    const unsigned short* __restrict__ sK, const unsigned short* __restrict__ sVt,
    unsigned short* __restrict__ sPw, int g, int r16, int wid, bool masked) {
    f32x4 s[4];
    __builtin_amdgcn_s_setprio(1);
    #pragma unroll
    for (int n = 0; n < 4; n++) {
        s[n] = (f32x4){0.f, 0.f, 0.f, 0.f};
        #pragma unroll
        for (int kc = 0; kc < 2; kc++) {
            int kv = n * 16 + r16;
            int bo = (kv * 128 + kc * 64 + g * 16) ^ ((kv & 7) << 4);
            bf16x8 kf = *(const bf16x8*)((const char*)sK + bo);
            s[n] = __builtin_amdgcn_mfma_f32_16x16x32_bf16(qf[kc], kf, s[n], 0, 0, 0);
        }
    }
    __builtin_amdgcn_s_setprio(0);
    if (masked) {
        #pragma unroll
        for (int n = 0; n < 4; n++)
            #pragma unroll
            for (int r = 0; r < 4; r++)
                s[n][r] = (n * 16 + r16 <= wid * 16 + g * 4 + r) ? s[n][r] : -1e30f;
    }
    #pragma unroll
    for (int n = 0; n < 4; n++)
        #pragma unroll
        for (int r = 0; r < 4; r++) s[n][r] = exp2f(s[n][r]);
    #pragma unroll
    for (int r = 0; r < 4; r++)
        pl[r] += (s[0][r] + s[1][r]) + (s[2][r] + s[3][r]);
    #pragma unroll
    for (int n = 0; n < 4; n++)
        #pragma unroll
        for (int r = 0; r < 4; r++) {
            int prow = g * 4 + r;
            int bo = (prow * 128 + (n * 16 + r16) * 2) ^ ((prow & 7) << 4);
            union { float f; unsigned u; } pv; pv.f = s[n][r];
            *(unsigned short*)((char*)sPw + bo) = (unsigned short)(pv.u >> 16);
        }
    __builtin_amdgcn_s_setprio(1);
    #pragma unroll
    for (int dt = 0; dt < 4; dt++) {
        #pragma unroll
        for (int kc = 0; kc < 2; kc++) {
            int bo = (r16 * 128 + kc * 64 + g * 16) ^ ((r16 & 7) << 4);
            bf16x8 pf = *(const bf16x8*)((const char*)sPw + bo);
            int dd = dt * 16 + r16;
            int bo2 = (dd * 128 + kc * 64 + g * 16) ^ ((dd & 7) << 4);
            bf16x8 vf = *(const bf16x8*)((const char*)sVt + bo2);
            oo[dt] = __builtin_amdgcn_mfma_f32_16x16x32_bf16(pf, vf, oo[dt], 0, 0, 0);
        }
    }
    __builtin_amdgcn_s_setprio(0);
}

__global__ __launch_bounds__(256, 4) void attn_fwd(
    const unsigned short* __restrict__ qkv, const unsigned short* __restrict__ vt,
    unsigned short* __restrict__ att,
    const float* __restrict__ ct, const float* __restrict__ st) {
    __shared__ unsigned short sK[2][64 * 64];
    __shared__ unsigned short sVt[2][64 * 64];
    __shared__ unsigned short sP[4][16 * 64];

    int tid = threadIdx.x;
    int wid = tid >> 6, lane = tid & 63;
    int g = lane >> 4, r16 = lane & 15;
    int qp = blockIdx.x;
    int bh = blockIdx.y;
    int b = bh >> 5, qh = bh & 31, kvh = qh >> 2;
    int qtA = qp, qtB = 31 - qp;

    const unsigned short* base = qkv + (size_t)b * Tn * NQKV;
    const unsigned short* kg = base + KOFF + kvh * 64;
    const unsigned short* vg = vt + (size_t)((b * 8 + kvh) * 64) * Tn;

    // Q fragments + in-register rope (+SCL). qf[0][e] = col g*8+e (p<32),
    // qf[1][e] = col 32+g*8+e — the rotation pair is lane-local.
    bf16x8 qfA[2], qfB[2];
    int qrA = qtA * 64 + wid * 16 + r16;
    int qrB = qtB * 64 + wid * 16 + r16;
    #pragma unroll
    for (int kc = 0; kc < 2; kc++) {
        qfA[kc] = *(const bf16x8*)(base + (size_t)qrA * NQKV + qh * 64 + kc * 32 + g * 8);
        qfB[kc] = *(const bf16x8*)(base + (size_t)qrB * NQKV + qh * 64 + kc * 32 + g * 8);
    }
    #pragma unroll
    for (int e = 0; e < 8; e++) {
        int p = g * 8 + e;
        float cA = ct[qrA * 32 + p], sA_ = st[qrA * 32 + p];
        float a0 = bf2f((unsigned short)qfA[0][e]), a1 = bf2f((unsigned short)qfA[1][e]);
        qfA[0][e] = (short)f2bf((a0 * cA - a1 * sA_) * SCL);
        qfA[1][e] = (short)f2bf((a1 * cA + a0 * sA_) * SCL);
        float cB = ct[qrB * 32 + p], sB_ = st[qrB * 32 + p];
        float b0 = bf2f((unsigned short)qfB[0][e]), b1 = bf2f((unsigned short)qfB[1][e]);
        qfB[0][e] = (short)f2bf((b0 * cB - b1 * sB_) * SCL);
        qfB[1][e] = (short)f2bf((b1 * cB + b0 * sB_) * SCL);
    }

    float plA[4], plB[4];
    f32x4 oA[4], oB[4];
    #pragma unroll
    for (int r = 0; r < 4; r++) { plA[r] = 0.f; plB[r] = 0.f; }
    #pragma unroll
    for (int d = 0; d < 4; d++) {
        oA[d] = (f32x4){0.f, 0.f, 0.f, 0.f};
        oB[d] = (f32x4){0.f, 0.f, 0.f, 0.f};
    }

    unsigned short* sPw = &sP[wid][0];

    #pragma unroll
    for (int jj = 0; jj < 2; jj++) {
        int c = wid * 2 + jj;
        int bo = c * 1024 + lane * 16;
        int row = bo >> 7;
        int coff = (bo & 127) ^ ((row & 7) << 4);
        GLOAD_LDS16(kg + (size_t)row * NQKV + (coff >> 1), (char*)&sK[0][0] + c * 1024);
        GLOAD_LDS16(vg + (size_t)row * Tn + (coff >> 1), (char*)&sVt[0][0] + c * 1024);
    }
    __syncthreads();

    int cur = 0;
    for (int j = 0; j <= qtB; j++) {
        if (j < qtB) {
            int nxt = cur ^ 1;
            #pragma unroll
            for (int jj = 0; jj < 2; jj++) {
                int c = wid * 2 + jj;
                int bo = c * 1024 + lane * 16;
                int row = bo >> 7;
                int coff = (bo & 127) ^ ((row & 7) << 4);
                GLOAD_LDS16(kg + (size_t)((j + 1) * 64 + row) * NQKV + (coff >> 1),
                            (char*)&sK[nxt][0] + c * 1024);
                GLOAD_LDS16(vg + (size_t)row * Tn + (j + 1) * 64 + (coff >> 1),
                            (char*)&sVt[nxt][0] + c * 1024);
            }
        }
        const unsigned short* sKc = &sK[cur][0];
        const unsigned short* sVc = &sVt[cur][0];
        if (j <= qtA) flash_step(qfA, plA, oA, sKc, sVc, sPw, g, r16, wid, j == qtA);
        flash_step(qfB, plB, oB, sKc, sVc, sPw, g, r16, wid, j == qtB);
        __syncthreads();
        cur ^= 1;
    }

    float lA[4], lB[4];
    #pragma unroll
    for (int r = 0; r < 4; r++) {
        float vA = plA[r], vB = plB[r];
        #pragma unroll
        for (int msk = 1; msk < 16; msk <<= 1) {
            vA += __shfl_xor(vA, msk, 64);
            vB += __shfl_xor(vB, msk, 64);
        }
        lA[r] = 1.0f / vA;
        lB[r] = 1.0f / vB;
    }
    #pragma unroll
    for (int dt = 0; dt < 4; dt++)
        #pragma unroll
        for (int r = 0; r < 4; r++) {
            int qgA = qtA * 64 + wid * 16 + g * 4 + r;
            int qgB = qtB * 64 + wid * 16 + g * 4 + r;
            att[(size_t)(b * Tn + qgA) * Cn + qh * 64 + dt * 16 + r16] = f2bf(oA[dt][r] * lA[r]);
            att[(size_t)(b * Tn + qgB) * Cn + qh * 64 + dt * 16 + r16] = f2bf(oB[dt][r] * lB[r]);
        }
}

// ---------------- launch ----------------
extern "C" void kernel_launch(void* const* d_in, const int* in_sizes, int n_in,
                              void* d_out, int out_size, void* d_ws, size_t ws_size,
                              hipStream_t stream) {
    const float* x  = (const float*)d_in[0];
    const float* Wq = (const float*)d_in[1];
    const float* Wk = (const float*)d_in[2];
    const float* Wv = (const float*)d_in[3];
    const float* Wo = (const float*)d_in[4];
    float* out = (float*)d_out;

    char* w = (char*)d_ws;
    unsigned short* Xb    = (unsigned short*)w; w += (size_t)Mn * Cn * 2;       // 16.8 MB
    unsigned short* Wqkvt = (unsigned short*)w; w += (size_t)NQKV * Cn * 2;     // 12.6 MB
    unsigned short* Wot   = (unsigned short*)w; w += (size_t)Cn * Cn * 2;       //  8.4 MB
    unsigned short* QKV   = (unsigned short*)w; w += (size_t)Mn * NQKV * 2;     // 25.2 MB
    unsigned short* ATT   = (unsigned short*)w; w += (size_t)Mn * Cn * 2;       // 16.8 MB
    unsigned short* Vt    = (unsigned short*)w; w += (size_t)Bn * NKVH * HDIM * Tn * 2;  // 4.2 MB
    float* ct = (float*)w; w += (size_t)Tn * 32 * 4;
    float* st = (float*)w; w += (size_t)Tn * 32 * 4;                            // total ~84.5 MB

    convert_f32_bf16<<<(Mn * Cn / 4) / 256, 256, 0, stream>>>(x, Xb, Mn * Cn / 4);
    dim3 tb(32, 8);
    transpose_wqkv<<<dim3(64, 96), tb, 0, stream>>>(Wq, Wk, Wv, Wqkvt);
    transpose_convert<<<dim3(64, 64), tb, 0, stream>>>(Wo, Wot, Cn, 2048);
    rope_tables<<<(Tn * 32) / 256, 256, 0, stream>>>(ct, st);

    // QKV GEMM: 256x192 tiles -> grid 16x16 = 256 blocks = exact CU fill.
    gemm_pipe<256, 192, 2, 4, true, false><<<dim3(NQKV / 192, Mn / 256), 512, 0, stream>>>(
        Xb, Wqkvt, QKV, nullptr, NQKV, Cn);
    rope_k<<<(Mn * 8 * 32) / 256, 256, 0, stream>>>(QKV, ct, st);
    transpose_v<<<dim3(Tn / 32, Bn * NKVH, 2), tb, 0, stream>>>(QKV, Vt);
    attn_fwd<<<dim3(16, Bn * NHEAD), 256, 0, stream>>>(QKV, Vt, ATT, ct, st);
    gemm_pipe<128, 128, 2, 2, false, false><<<dim3(Cn / 128, Mn / 128), 256, 0, stream>>>(
        ATT, Wot, nullptr, out, Cn, Cn);
}

// Round 29
// 213.057 us; speedup vs baseline: 1.0037x; 1.0018x over previous
//
#include <hip/hip_runtime.h>
#include <stdint.h>

#define Bn 2
#define Tn 2048
#define Cn 2048
#define NHEAD 32
#define NKVH 8
#define HDIM 64
#define Mn (Bn*Tn)        // 4096
#define NQKV 3072         // 2048 Q | 512 K | 512 V
#define KOFF 2048
#define VOFF 2560

typedef __attribute__((ext_vector_type(8))) short bf16x8;
typedef __attribute__((ext_vector_type(4))) float f32x4;

#define AS1 __attribute__((address_space(1)))
#define AS3 __attribute__((address_space(3)))
#define GLOAD_LDS16(g, l) __builtin_amdgcn_global_load_lds((const AS1 void*)(g), (AS3 void*)(l), 16, 0, 0)

#define SCL 0.18033688f  /* 0.125 * log2(e) — folded into Q during attn's in-register rope */

#define SYNC_FENCE() __builtin_amdgcn_sched_barrier(0)
#define WAIT_VM_N(N_) do { asm volatile("s_waitcnt vmcnt(" #N_ ")" ::: "memory"); SYNC_FENCE(); } while (0)
#define BARRIER_RAW() do { __builtin_amdgcn_s_barrier(); SYNC_FENCE(); } while (0)

__device__ __forceinline__ unsigned short f2bf(float f) {
    union { float f; unsigned u; } v; v.f = f;
    return (unsigned short)((v.u + 0x7fffu + ((v.u >> 16) & 1u)) >> 16);
}
__device__ __forceinline__ float bf2f(unsigned short b) {
    union { unsigned u; float f; } v; v.u = ((unsigned)b) << 16;
    return v.f;
}

// ---------------- elementwise fp32 -> bf16 (vectorized) ----------------
__global__ void convert_f32_bf16(const float* __restrict__ src,
                                 unsigned short* __restrict__ dst, int n4) {
    int i = blockIdx.x * blockDim.x + threadIdx.x;
    if (i >= n4) return;
    float4 f = ((const float4*)src)[i];
    ushort4 o;
    o.x = f2bf(f.x); o.y = f2bf(f.y); o.z = f2bf(f.z); o.w = f2bf(f.w);
    ((ushort4*)dst)[i] = o;
}

// ---------------- transpose + convert: src (K x N) fp32 -> dst (N x K) bf16 ----------------
__global__ void transpose_convert(const float* __restrict__ src,
                                  unsigned short* __restrict__ dst, int K, int N) {
    __shared__ float tile[32][33];
    int k0 = blockIdx.x * 32, n0 = blockIdx.y * 32;
    int tx = threadIdx.x, ty = threadIdx.y;  // 32 x 8
    #pragma unroll
    for (int yy = 0; yy < 32; yy += 8)
        tile[ty + yy][tx] = src[(size_t)(k0 + ty + yy) * N + n0 + tx];
    __syncthreads();
    #pragma unroll
    for (int yy = 0; yy < 32; yy += 8)
        dst[(size_t)(n0 + ty + yy) * K + k0 + tx] = f2bf(tile[tx][ty + yy]);
}

// ---------------- merged Wq|Wk|Wv transpose -> Wqkvt[3072][2048] ----------------
__global__ void transpose_wqkv(const float* __restrict__ Wq, const float* __restrict__ Wk,
                               const float* __restrict__ Wv, unsigned short* __restrict__ dst) {
    __shared__ float tile[32][33];
    int k0 = blockIdx.x * 32, n0 = blockIdx.y * 32;  // n0 in [0,3072)
    const float* src; int srcN, c0;
    if (n0 < 2048)      { src = Wq; srcN = 2048; c0 = n0; }
    else if (n0 < 2560) { src = Wk; srcN = 512;  c0 = n0 - 2048; }
    else                { src = Wv; srcN = 512;  c0 = n0 - 2560; }
    int tx = threadIdx.x, ty = threadIdx.y;  // 32 x 8
    #pragma unroll
    for (int yy = 0; yy < 32; yy += 8)
        tile[ty + yy][tx] = src[(size_t)(k0 + ty + yy) * srcN + c0 + tx];
    __syncthreads();
    #pragma unroll
    for (int yy = 0; yy < 32; yy += 8)
        dst[(size_t)(n0 + ty + yy) * Cn + k0 + tx] = f2bf(tile[tx][ty + yy]);
}

// ---------------- RoPE tables: ct/st [Tn][32] fp32 ----------------
__global__ void rope_tables(float* __restrict__ ct, float* __restrict__ st) {
    int i = blockIdx.x * blockDim.x + threadIdx.x;  // Tn*32
    int t = i >> 5, d = i & 31;
    float invf = powf(10000.0f, -(float)d / 32.0f);
    float f = (float)t * invf;
    ct[i] = cosf(f);
    st[i] = sinf(f);
}

// ---------------- RoPE in-place on K heads only (no scale) ----------------
__global__ void rope_k(unsigned short* __restrict__ qkv,
                       const float* __restrict__ ct, const float* __restrict__ st) {
    int i = blockIdx.x * blockDim.x + threadIdx.x;  // Mn * 8 * 32
    int p = i & 31;
    int kvh = (i >> 5) & 7;
    int bt = i >> 8;
    int t = bt & (Tn - 1);
    size_t base = (size_t)bt * NQKV + KOFF + kvh * 64;
    float v0 = bf2f(qkv[base + p]);
    float v1 = bf2f(qkv[base + p + 32]);
    float c = ct[t * 32 + p], s = st[t * 32 + p];
    qkv[base + p]      = f2bf(v0 * c - v1 * s);
    qkv[base + p + 32] = f2bf(v1 * c + v0 * s);
}

// ---------------- V transpose: QKV V-part -> Vt[b][kvh][d][t] (bf16) ----------------
__global__ void transpose_v(const unsigned short* __restrict__ qkv,
                            unsigned short* __restrict__ vt) {
    __shared__ unsigned short tile[32][33];
    int t0 = blockIdx.x * 32;
    int b = blockIdx.y >> 3, kvh = blockIdx.y & 7;
    int d0 = blockIdx.z * 32;
    int tx = threadIdx.x, ty = threadIdx.y;  // 32 x 8
    #pragma unroll
    for (int yy = 0; yy < 32; yy += 8)
        tile[ty + yy][tx] = qkv[(size_t)(b * Tn + t0 + ty + yy) * NQKV + VOFF + kvh * 64 + d0 + tx];
    __syncthreads();
    #pragma unroll
    for (int yy = 0; yy < 32; yy += 8)
        vt[(size_t)((b * 8 + kvh) * 64 + d0 + ty + yy) * Tn + t0 + tx] = tile[tx][ty + yy];
}

// ---------------- Pipelined GEMM template: C = A[M,K] @ Bt[N,K]^T ----------------
// BK=64, double-buffered LDS, counted-vmcnt schedule (loads never drained to 0
// in the main loop), raw barriers. BF16OUT selects output dtype.
template <int BM, int BN, int WMv, int WNv, bool BF16OUT, bool SWZ>
__global__ __launch_bounds__(WMv * WNv * 64, 2) void gemm_pipe(
    const unsigned short* __restrict__ A, const unsigned short* __restrict__ Bt,
    unsigned short* __restrict__ outb, float* __restrict__ outf, int N, int K) {
    constexpr int THREADS = WMv * WNv * 64;
    constexpr int MR = BM / WMv / 16;           // m-frags per wave
    constexpr int NR = BN / WNv / 16;           // n-frags per wave
    constexpr int LA = (BM * 64 * 2) / (THREADS * 16);  // A gload_lds per thread
    constexpr int LB = (BN * 64 * 2) / (THREADS * 16);  // B gload_lds per thread

    __shared__ unsigned short sA[2][BM * 64];
    __shared__ unsigned short sB[2][BN * 64];

    int tid = threadIdx.x;
    int wid = tid >> 6, lane = tid & 63;
    int wm = wid / WNv, wn = wid % WNv;
    int g = lane >> 4, r16 = lane & 15;

    int bx, by;
    if (SWZ) {
        int nwg = gridDim.x * gridDim.y;
        int lid = blockIdx.y * gridDim.x + blockIdx.x;
        int swz = (lid & 7) * (nwg >> 3) + (lid >> 3);
        bx = swz % gridDim.x; by = swz / gridDim.x;
    } else {
        bx = blockIdx.x; by = blockIdx.y;
    }
    int brow = by * BM, bcol = bx * BN;

    int NT = K / 64;

    auto stage = [&](int kt, int b) {
        #pragma unroll
        for (int li = 0; li < LA; li++) {
            int cb = li * (THREADS * 16) + wid * 1024;
            int bo = cb + lane * 16;
            int row = bo >> 7;
            int coff = (bo & 127) ^ ((row & 7) << 4);
            GLOAD_LDS16(A + (size_t)(brow + row) * K + kt * 64 + (coff >> 1),
                        (char*)&sA[b][0] + cb);
        }
        #pragma unroll
        for (int li = 0; li < LB; li++) {
            int cb = li * (THREADS * 16) + wid * 1024;
            int bo = cb + lane * 16;
            int row = bo >> 7;
            int coff = (bo & 127) ^ ((row & 7) << 4);
            GLOAD_LDS16(Bt + (size_t)(bcol + row) * K + kt * 64 + (coff >> 1),
                        (char*)&sB[b][0] + cb);
        }
    };

    f32x4 acc[MR][NR];
    #pragma unroll
    for (int m = 0; m < MR; m++)
        #pragma unroll
        for (int n = 0; n < NR; n++) acc[m][n] = (f32x4){0.f, 0.f, 0.f, 0.f};

    stage(0, 0);
    stage(1, 1);

    for (int kt = 0; kt < NT; kt++) {
        if (kt + 1 < NT) {
            if (LA + LB == 8) { WAIT_VM_N(8); } else { WAIT_VM_N(7); }
        } else {
            WAIT_VM_N(0);
        }
        BARRIER_RAW();                       // all waves' kt tile resident
        const char* cA = (const char*)&sA[kt & 1][0];
        const char* cB = (const char*)&sB[kt & 1][0];
        bf16x8 av[MR][2];
        #pragma unroll
        for (int m = 0; m < MR; m++)
            #pragma unroll
            for (int kc = 0; kc < 2; kc++) {
                int row = wm * (MR * 16) + m * 16 + r16;
                int byo = (row * 128 + kc * 64 + g * 16) ^ ((row & 7) << 4);
                av[m][kc] = *(const bf16x8*)(cA + byo);
            }
        #pragma unroll
        for (int n = 0; n < NR; n++) {
            bf16x8 bv[2];
            #pragma unroll
            for (int kc = 0; kc < 2; kc++) {
                int row = wn * (NR * 16) + n * 16 + r16;
                int byo = (row * 128 + kc * 64 + g * 16) ^ ((row & 7) << 4);
                bv[kc] = *(const bf16x8*)(cB + byo);
            }
            __builtin_amdgcn_s_setprio(1);
            #pragma unroll
            for (int m = 0; m < MR; m++)
                #pragma unroll
                for (int kc = 0; kc < 2; kc++)
                    acc[m][n] = __builtin_amdgcn_mfma_f32_16x16x32_bf16(av[m][kc], bv[kc], acc[m][n], 0, 0, 0);
            __builtin_amdgcn_s_setprio(0);
        }
        BARRIER_RAW();                       // all waves done reading buf[kt&1]
        if (kt + 2 < NT) stage(kt + 2, kt & 1);
        SYNC_FENCE();
    }

    #pragma unroll
    for (int m = 0; m < MR; m++) {
        #pragma unroll
        for (int n = 0; n < NR; n++) {
            int row0 = brow + wm * (MR * 16) + m * 16 + g * 4;
            int col = bcol + wn * (NR * 16) + n * 16 + r16;
            #pragma unroll
            for (int r = 0; r < 4; r++) {
                if (BF16OUT)
                    outb[(size_t)(row0 + r) * N + col] = f2bf(acc[m][n][r]);
                else
                    outf[(size_t)(row0 + r) * N + col] = acc[m][n][r];
            }
        }
    }
}

// ---------------- Flash attention: causal, GQA 4:1, hd=64 ----------------
// 64-row q-tiles, fold-pair {qp, 31-qp}, 4 blocks/CU. Q rope (+SCL) applied
// in-register at Q-fragment load (pairs (p,p+32) are lane-local across qf[0]/qf[1]).
// No-max softmax (P = exp2(s) directly), per-lane denominator partials.
// Double-buffered K/V staging; s_setprio(1) around MFMA clusters (T5).
__device__ __forceinline__ void flash_step(
    const bf16x8 (&qf)[2], float (&pl)[4], f32x4 (&oo)[4],
    const unsigned short* __restrict__ sK, const unsigned short* __restrict__ sVt,
    unsigned short* __restrict__ sPw, int g, int r16, int wid, bool masked) {
    f32x4 s[4];
    __builtin_amdgcn_s_setprio(1);
    #pragma unroll
    for (int n = 0; n < 4; n++) {
        s[n] = (f32x4){0.f, 0.f, 0.f, 0.f};
        #pragma unroll
        for (int kc = 0; kc < 2; kc++) {
            int kv = n * 16 + r16;
            int bo = (kv * 128 + kc * 64 + g * 16) ^ ((kv & 7) << 4);
            bf16x8 kf = *(const bf16x8*)((const char*)sK + bo);
            s[n] = __builtin_amdgcn_mfma_f32_16x16x32_bf16(qf[kc], kf, s[n], 0, 0, 0);
        }
    }
    __builtin_amdgcn_s_setprio(0);
    if (masked) {
        #pragma unroll
        for (int n = 0; n < 4; n++)
            #pragma unroll
            for (int r = 0; r < 4; r++)
                s[n][r] = (n * 16 + r16 <= wid * 16 + g * 4 + r) ? s[n][r] : -1e30f;
    }
    #pragma unroll
    for (int n = 0; n < 4; n++)
        #pragma unroll
        for (int r = 0; r < 4; r++) s[n][r] = exp2f(s[n][r]);
    #pragma unroll
    for (int r = 0; r < 4; r++)
        pl[r] += (s[0][r] + s[1][r]) + (s[2][r] + s[3][r]);
    #pragma unroll
    for (int n = 0; n < 4; n++)
        #pragma unroll
        for (int r = 0; r < 4; r++) {
            int prow = g * 4 + r;
            int bo = (prow * 128 + (n * 16 + r16) * 2) ^ ((prow & 7) << 4);
            union { float f; unsigned u; } pv; pv.f = s[n][r];
            *(unsigned short*)((char*)sPw + bo) = (unsigned short)(pv.u >> 16);
        }
    __builtin_amdgcn_s_setprio(1);
    #pragma unroll
    for (int dt = 0; dt < 4; dt++) {
        #pragma unroll
        for (int kc = 0; kc < 2; kc++) {
            int bo = (r16 * 128 + kc * 64 + g * 16) ^ ((r16 & 7) << 4);
            bf16x8 pf = *(const bf16x8*)((const char*)sPw + bo);
            int dd = dt * 16 + r16;
            int bo2 = (dd * 128 + kc * 64 + g * 16) ^ ((dd & 7) << 4);
            bf16x8 vf = *(const bf16x8*)((const char*)sVt + bo2);
            oo[dt] = __builtin_amdgcn_mfma_f32_16x16x32_bf16(pf, vf, oo[dt], 0, 0, 0);
        }
    }
    __builtin_amdgcn_s_setprio(0);
}

__global__ __launch_bounds__(256, 4) void attn_fwd(
    const unsigned short* __restrict__ qkv, const unsigned short* __restrict__ vt,
    unsigned short* __restrict__ att,
    const float* __restrict__ ct, const float* __restrict__ st) {
    __shared__ unsigned short sK[2][64 * 64];
    __shared__ unsigned short sVt[2][64 * 64];
    __shared__ unsigned short sP[4][16 * 64];

    int tid = threadIdx.x;
    int wid = tid >> 6, lane = tid & 63;
    int g = lane >> 4, r16 = lane & 15;
    int qp = blockIdx.x;
    int bh = blockIdx.y;
    int b = bh >> 5, qh = bh & 31, kvh = qh >> 2;
    int qtA = qp, qtB = 31 - qp;

    const unsigned short* base = qkv + (size_t)b * Tn * NQKV;
    const unsigned short* kg = base + KOFF + kvh * 64;
    const unsigned short* vg = vt + (size_t)((b * 8 + kvh) * 64) * Tn;

    // Q fragments + in-register rope (+SCL). qf[0][e] = col g*8+e (p<32),
    // qf[1][e] = col 32+g*8+e — the rotation pair is lane-local.
    bf16x8 qfA[2], qfB[2];
    int qrA = qtA * 64 + wid * 16 + r16;
    int qrB = qtB * 64 + wid * 16 + r16;
    #pragma unroll
    for (int kc = 0; kc < 2; kc++) {
        qfA[kc] = *(const bf16x8*)(base + (size_t)qrA * NQKV + qh * 64 + kc * 32 + g * 8);
        qfB[kc] = *(const bf16x8*)(base + (size_t)qrB * NQKV + qh * 64 + kc * 32 + g * 8);
    }
    #pragma unroll
    for (int e = 0; e < 8; e++) {
        int p = g * 8 + e;
        float cA = ct[qrA * 32 + p], sA_ = st[qrA * 32 + p];
        float a0 = bf2f((unsigned short)qfA[0][e]), a1 = bf2f((unsigned short)qfA[1][e]);
        qfA[0][e] = (short)f2bf((a0 * cA - a1 * sA_) * SCL);
        qfA[1][e] = (short)f2bf((a1 * cA + a0 * sA_) * SCL);
        float cB = ct[qrB * 32 + p], sB_ = st[qrB * 32 + p];
        float b0 = bf2f((unsigned short)qfB[0][e]), b1 = bf2f((unsigned short)qfB[1][e]);
        qfB[0][e] = (short)f2bf((b0 * cB - b1 * sB_) * SCL);
        qfB[1][e] = (short)f2bf((b1 * cB + b0 * sB_) * SCL);
    }

    float plA[4], plB[4];
    f32x4 oA[4], oB[4];
    #pragma unroll
    for (int r = 0; r < 4; r++) { plA[r] = 0.f; plB[r] = 0.f; }
    #pragma unroll
    for (int d = 0; d < 4; d++) {
        oA[d] = (f32x4){0.f, 0.f, 0.f, 0.f};
        oB[d] = (f32x4){0.f, 0.f, 0.f, 0.f};
    }

    unsigned short* sPw = &sP[wid][0];

    #pragma unroll
    for (int jj = 0; jj < 2; jj++) {
        int c = wid * 2 + jj;
        int bo = c * 1024 + lane * 16;
        int row = bo >> 7;
        int coff = (bo & 127) ^ ((row & 7) << 4);
        GLOAD_LDS16(kg + (size_t)row * NQKV + (coff >> 1), (char*)&sK[0][0] + c * 1024);
        GLOAD_LDS16(vg + (size_t)row * Tn + (coff >> 1), (char*)&sVt[0][0] + c * 1024);
    }
    __syncthreads();

    int cur = 0;
    for (int j = 0; j <= qtB; j++) {
        if (j < qtB) {
            int nxt = cur ^ 1;
            #pragma unroll
            for (int jj = 0; jj < 2; jj++) {
                int c = wid * 2 + jj;
                int bo = c * 1024 + lane * 16;
                int row = bo >> 7;
                int coff = (bo & 127) ^ ((row & 7) << 4);
                GLOAD_LDS16(kg + (size_t)((j + 1) * 64 + row) * NQKV + (coff >> 1),
                            (char*)&sK[nxt][0] + c * 1024);
                GLOAD_LDS16(vg + (size_t)row * Tn + (j + 1) * 64 + (coff >> 1),
                            (char*)&sVt[nxt][0] + c * 1024);
            }
        }
        const unsigned short* sKc = &sK[cur][0];
        const unsigned short* sVc = &sVt[cur][0];
        if (j <= qtA) flash_step(qfA, plA, oA, sKc, sVc, sPw, g, r16, wid, j == qtA);
        flash_step(qfB, plB, oB, sKc, sVc, sPw, g, r16, wid, j == qtB);
        __syncthreads();
        cur ^= 1;
    }

    float lA[4], lB[4];
    #pragma unroll
    for (int r = 0; r < 4; r++) {
        float vA = plA[r], vB = plB[r];
        #pragma unroll
        for (int msk = 1; msk < 16; msk <<= 1) {
            vA += __shfl_xor(vA, msk, 64);
            vB += __shfl_xor(vB, msk, 64);
        }
        lA[r] = 1.0f / vA;
        lB[r] = 1.0f / vB;
    }
    #pragma unroll
    for (int dt = 0; dt < 4; dt++)
        #pragma unroll
        for (int r = 0; r < 4; r++) {
            int qgA = qtA * 64 + wid * 16 + g * 4 + r;
            int qgB = qtB * 64 + wid * 16 + g * 4 + r;
            att[(size_t)(b * Tn + qgA) * Cn + qh * 64 + dt * 16 + r16] = f2bf(oA[dt][r] * lA[r]);
            att[(size_t)(b * Tn + qgB) * Cn + qh * 64 + dt * 16 + r16] = f2bf(oB[dt][r] * lB[r]);
        }
}

// ---------------- launch ----------------
extern "C" void kernel_launch(void* const* d_in, const int* in_sizes, int n_in,
                              void* d_out, int out_size, void* d_ws, size_t ws_size,
                              hipStream_t stream) {
    const float* x  = (const float*)d_in[0];
    const float* Wq = (const float*)d_in[1];
    const float* Wk = (const float*)d_in[2];
    const float* Wv = (const float*)d_in[3];
    const float* Wo = (const float*)d_in[4];
    float* out = (float*)d_out;

    char* w = (char*)d_ws;
    unsigned short* Xb    = (unsigned short*)w; w += (size_t)Mn * Cn * 2;       // 16.8 MB
    unsigned short* Wqkvt = (unsigned short*)w; w += (size_t)NQKV * Cn * 2;     // 12.6 MB
    unsigned short* Wot   = (unsigned short*)w; w += (size_t)Cn * Cn * 2;       //  8.4 MB
    unsigned short* QKV   = (unsigned short*)w; w += (size_t)Mn * NQKV * 2;     // 25.2 MB
    unsigned short* ATT   = (unsigned short*)w; w += (size_t)Mn * Cn * 2;       // 16.8 MB
    unsigned short* Vt    = (unsigned short*)w; w += (size_t)Bn * NKVH * HDIM * Tn * 2;  // 4.2 MB
    float* ct = (float*)w; w += (size_t)Tn * 32 * 4;
    float* st = (float*)w; w += (size_t)Tn * 32 * 4;                            // total ~84.5 MB

    convert_f32_bf16<<<(Mn * Cn / 4) / 256, 256, 0, stream>>>(x, Xb, Mn * Cn / 4);
    dim3 tb(32, 8);
    transpose_wqkv<<<dim3(64, 96), tb, 0, stream>>>(Wq, Wk, Wv, Wqkvt);
    transpose_convert<<<dim3(64, 64), tb, 0, stream>>>(Wo, Wot, Cn, 2048);
    rope_tables<<<(Tn * 32) / 256, 256, 0, stream>>>(ct, st);

    // QKV GEMM: 256x192 tiles -> grid 16x16 = 256 blocks = exact CU fill.
    gemm_pipe<256, 192, 2, 4, true, false><<<dim3(NQKV / 192, Mn / 256), 512, 0, stream>>>(
        Xb, Wqkvt, QKV, nullptr, NQKV, Cn);
    rope_k<<<(Mn * 8 * 32) / 256, 256, 0, stream>>>(QKV, ct, st);
    transpose_v<<<dim3(Tn / 32, Bn * NKVH, 2), tb, 0, stream>>>(QKV, Vt);
    attn_fwd<<<dim3(16, Bn * NHEAD), 256, 0, stream>>>(QKV, Vt, ATT, ct, st);
    gemm_pipe<128, 128, 2, 2, false, false><<<dim3(Cn / 128, Mn / 128), 256, 0, stream>>>(
        ATT, Wot, nullptr, out, Cn, Cn);
}